// Round 6
// baseline (117.009 us; speedup 1.0000x reference)
//
#include <hip/hip_runtime.h>
#include <math.h>

// B=2, C=1, H=W=2048, RADIUS=1, RK=3; J center plane is zeroed in setup.
namespace {
constexpr int H = 2048;
constexpr int W = 2048;
constexpr int NPIX = H * W;            // 2^22
constexpr int B = 2;
constexpr float DECf = 0.95f;
constexpr float OMDf = 1.0f - 0.95f;
}

using f2 = __attribute__((ext_vector_type(2))) float;

// R6: J-read-once (R5) + restored wave count (R3).
// Grid = H*4 = 8192 quarter-row blocks, 256 thr, 2 px/thread x 2 batches.
// R5 halved the wave count (16384) and effective BW fell 4.05->3.35 TB/s;
// this brings back 32768 waves (memory-level concurrency) while J and
// rand_drop are still loaded exactly once per position and used for both
// batches. float2 loads = 8 B/lane (coalescing sweet spot).
// XCD-chunked bijective swizzle (8192 % 8 == 0): adjacent rows same XCD-L2.
// Numerics: decision path (tap-sum in tap order, delta_e, exp, compare) in
// f64 (passed 5x); EMA observables in f32 (passed R3-R5, absmax 0.0078).
__global__ __launch_bounds__(256) void ising_step_kernel(
    const float* __restrict__ x,      // (B, 2, H, W): s then b
    const float* __restrict__ obvs,   // (B, 4, H, W): e, e2, c, m
    const float* __restrict__ Jm,     // (1, 9, N)
    const float* __restrict__ rs,     // (B, 1, H, W)
    const float* __restrict__ rd,     // (1, 1, H, W)
    float* __restrict__ out)          // state (B,2,N) ++ obvs_out (B,4,N)
{
  const int bid = blockIdx.x;
  const int u   = ((bid & 7) << 10) | (bid >> 3);  // 8 XCDs x 1024 units
  const int h   = u >> 2;                          // row
  const int qtr = u & 3;                           // quarter of the row
  const int w0  = (qtr << 9) | (threadIdx.x << 1); // 2 px per thread
  const int n0  = (h << 11) | w0;

  const int hm = (h - 1) & (H - 1);
  const int hp = (h + 1) & (H - 1);
  const int wl = (w0 - 1) & (W - 1);
  const int wr = (w0 + 2) & (W - 1);

  // ---- batch-independent loads: 8 J planes + rand_drop (used twice) ----
  f2 jv[8];
  #pragma unroll
  for (int k = 0; k < 8; ++k) {
    const int kk = (k < 4) ? k : (k + 1);   // skip zeroed center plane
    jv[k] = *(const f2*)(Jm + (size_t)kk * NPIX + n0);
  }
  const f2 dv = *(const f2*)(rd + n0);

  // ---- per-batch loads (issued before compute) ----
  f2 vm[2], vc[2], vp[2], bv[2], ev[2], e2v[2], cv[2], mv[2], rv[2];
  float lm[2], rmh[2], lc[2], rch[2], lp[2], rph[2];
  #pragma unroll
  for (int bi = 0; bi < 2; ++bi) {
    const float* sb   = x + (size_t)bi * 2 * NPIX;
    const float* rowm = sb + (size_t)hm * W;
    const float* rowc = sb + (size_t)h  * W;
    const float* rowp = sb + (size_t)hp * W;
    vm[bi] = *(const f2*)(rowm + w0);
    vc[bi] = *(const f2*)(rowc + w0);
    vp[bi] = *(const f2*)(rowp + w0);
    lm[bi] = rowm[wl];  rmh[bi] = rowm[wr];
    lc[bi] = rowc[wl];  rch[bi] = rowc[wr];
    lp[bi] = rowp[wl];  rph[bi] = rowp[wr];
    bv[bi] = *(const f2*)(sb + (size_t)NPIX + n0);
    const float* ob = obvs + (size_t)bi * 4 * NPIX + n0;
    ev[bi]  = *(const f2*)(ob);
    e2v[bi] = *(const f2*)(ob + (size_t)NPIX);
    cv[bi]  = *(const f2*)(ob + 2 * (size_t)NPIX);
    mv[bi]  = *(const f2*)(ob + 3 * (size_t)NPIX);
    rv[bi]  = *(const f2*)(rs + (size_t)bi * NPIX + n0);
  }

  // ---- compute + store per batch ----
  #pragma unroll
  for (int bi = 0; bi < 2; ++bi) {
    const float am[4] = {lm[bi], vm[bi].x, vm[bi].y, rmh[bi]};
    const float ac[4] = {lc[bi], vc[bi].x, vc[bi].y, rch[bi]};
    const float ap[4] = {lp[bi], vp[bi].x, vp[bi].y, rph[bi]};
    const float bq[2]  = {bv[bi].x, bv[bi].y};
    const float eq[2]  = {ev[bi].x, ev[bi].y};
    const float e2q[2] = {e2v[bi].x, e2v[bi].y};
    const float cq[2]  = {cv[bi].x, cv[bi].y};
    const float mq[2]  = {mv[bi].x, mv[bi].y};
    const float rsq[2] = {rv[bi].x, rv[bi].y};
    const float rdq[2] = {dv.x, dv.y};

    float so[2], eo[2], e2o[2], co[2], mo[2];
    #pragma unroll
    for (int t = 0; t < 2; ++t) {
      // decision-critical path in f64, reference tap order
      const double sum =
          (double)jv[0][t] * am[t]     + (double)jv[1][t] * am[t + 1] +
          (double)jv[2][t] * am[t + 2] + (double)jv[3][t] * ac[t]     +
          (double)jv[4][t] * ac[t + 2] + (double)jv[5][t] * ap[t]     +
          (double)jv[6][t] * ap[t + 1] + (double)jv[7][t] * ap[t + 2];
      const float sf  = ac[t + 1];
      const double s  = (double)sf;
      const double de = 2.0 * s * sum;
      const double p  = (de <= 0.0) ? 1.0 : exp(-de * (double)bq[t]);
      const bool acc  = ((double)rsq[t] < p) && (rdq[t] > 0.5f);
      // observables in f32
      const float E   = (float)(-s * sum);
      const float bf  = bq[t];
      const float en  = DECf * eq[t]  + OMDf * E;
      const float e2n = DECf * e2q[t] + OMDf * E * E;
      const float cn  = DECf * cq[t]  + OMDf * (e2n - en * en) * bf * bf;
      const float mn  = DECf * mq[t]  + OMDf * sf;
      so[t]  = acc ? -sf : sf;
      eo[t]  = en;
      e2o[t] = e2n;
      co[t]  = cn;
      mo[t]  = mn;
    }

    float* st = out + (size_t)bi * 2 * NPIX;
    float* oo = out + (size_t)B * 2 * NPIX + (size_t)bi * 4 * NPIX;
    *(f2*)(st + n0)                     = (f2){so[0], so[1]};
    *(f2*)(st + (size_t)NPIX + n0)      = bv[bi];
    *(f2*)(oo + n0)                     = (f2){eo[0], eo[1]};
    *(f2*)(oo + (size_t)NPIX + n0)      = (f2){e2o[0], e2o[1]};
    *(f2*)(oo + 2 * (size_t)NPIX + n0)  = (f2){co[0], co[1]};
    *(f2*)(oo + 3 * (size_t)NPIX + n0)  = (f2){mo[0], mo[1]};
  }
}

extern "C" void kernel_launch(void* const* d_in, const int* in_sizes, int n_in,
                              void* d_out, int out_size, void* d_ws, size_t ws_size,
                              hipStream_t stream) {
  const float* x    = (const float*)d_in[0];
  const float* obvs = (const float*)d_in[1];
  const float* Jm   = (const float*)d_in[2];
  const float* rs   = (const float*)d_in[3];
  const float* rd   = (const float*)d_in[4];
  float* out = (float*)d_out;

  constexpr int grid = H * 4;   // 8192 quarter-row blocks, both batches each
  ising_step_kernel<<<grid, 256, 0, stream>>>(x, obvs, Jm, rs, rd, out);
}